// Round 1
// baseline (702.934 us; speedup 1.0000x reference)
//
#include <hip/hip_runtime.h>

typedef __attribute__((ext_vector_type(8))) short short8;
typedef __attribute__((ext_vector_type(4))) float f32x4;

__device__ __forceinline__ unsigned short f2b(float f){
  union { float f; unsigned u; } x; x.f = f;
  unsigned r = x.u + 0x7fffu + ((x.u >> 16) & 1u);
  return (unsigned short)(r >> 16);
}
__device__ __forceinline__ float b2f(unsigned short v){
  union { unsigned u; float f; } x; x.u = ((unsigned)v) << 16; return x.f;
}

// ---------------- CSR build ----------------
__global__ void count_k(const int* __restrict__ dst, int* __restrict__ deg, int E){
  int e = blockIdx.x*256 + threadIdx.x;
  if (e < E) atomicAdd(&deg[dst[e]], 1);
}

__global__ void scan_k(const int* __restrict__ deg, int* __restrict__ rowstart,
                       int* __restrict__ cursor, int n)
{
  __shared__ int wsum[16];
  __shared__ int carry_s;
  int tid = threadIdx.x, lane = tid & 63, wv = tid >> 6;
  if (tid == 0) carry_s = 0;
  __syncthreads();
  for (int base = 0; base < n; base += 1024){
    int i = base + tid;
    int v = (i < n) ? deg[i] : 0;
    int xv = v;
    #pragma unroll
    for (int o=1;o<64;o<<=1){ int t = __shfl_up(xv, o, 64); if (lane >= o) xv += t; }
    if (lane == 63) wsum[wv] = xv;
    __syncthreads();
    if (tid < 16){
      int w = wsum[tid];
      #pragma unroll
      for (int o=1;o<16;o<<=1){ int t = __shfl_up(w, o, 64); if (tid >= o) w += t; }
      wsum[tid] = w;
    }
    __syncthreads();
    int woff = (wv == 0) ? 0 : wsum[wv-1];
    int carry = carry_s;
    if (i < n){ int excl = carry + woff + xv - v; rowstart[i] = excl; cursor[i] = excl; }
    int total = wsum[15];
    __syncthreads();
    if (tid == 0) carry_s = carry + total;
    __syncthreads();
  }
  if (threadIdx.x == 0) rowstart[n] = carry_s;
}

__global__ void fill_k(const int* __restrict__ src, const int* __restrict__ dst,
                       int* __restrict__ cursor, int* __restrict__ csrc, int E){
  int e = blockIdx.x*256 + threadIdx.x;
  if (e < E){
    int p = atomicAdd(&cursor[dst[e]], 1);
    csrc[p] = src[e];
  }
}

// ---------------- weight transpose + bf16 convert: Wt[o][i] = W[i][o] ----------------
__global__ void transpose_k(const float* __restrict__ W, unsigned short* __restrict__ Wt,
                            int r, int c){
  int idx = blockIdx.x*256 + threadIdx.x;
  int total = c * (r >> 3);
  if (idx >= total) return;
  int o = idx % c;
  int i0 = (idx / c) << 3;
  short8 vv;
  #pragma unroll
  for (int j=0;j<8;j++) ((unsigned short*)&vv)[j] = f2b(W[(size_t)(i0+j)*c + o]);
  *(short8*)&Wt[(size_t)o*r + i0] = vv;
}

// ---------------- f32 -> bf16 convert ----------------
__global__ void cvt_k(const float* __restrict__ in, unsigned short* __restrict__ out, size_t n){
  size_t i = ((size_t)blockIdx.x*256 + threadIdx.x)*8;
  if (i >= n) return;
  const float4* p = (const float4*)(in + i);
  float4 a0 = p[0], a1 = p[1];
  short8 vv;
  ((unsigned short*)&vv)[0] = f2b(a0.x); ((unsigned short*)&vv)[1] = f2b(a0.y);
  ((unsigned short*)&vv)[2] = f2b(a0.z); ((unsigned short*)&vv)[3] = f2b(a0.w);
  ((unsigned short*)&vv)[4] = f2b(a1.x); ((unsigned short*)&vv)[5] = f2b(a1.y);
  ((unsigned short*)&vv)[6] = f2b(a1.z); ((unsigned short*)&vv)[7] = f2b(a1.w);
  *(short8*)&out[i] = vv;
}

// ---------------- GEMM: A[M][K] bf16 x Bt[Nout][K] bf16 -> epilogue ----------------
// MODE 0: QKVS  (bias split over 4 ranges; cols<1536 -> bf16 qkv[row][col], else f32 skip)
// MODE 1: FFN1  (bias + relu -> bf16 out[row][Nout])
// MODE 2: FFN2  (bias + res  -> f32 out[row][512])
template<int MODE>
__global__ __launch_bounds__(256) void gemm_k(
    const unsigned short* __restrict__ A,
    const unsigned short* __restrict__ Bt,
    int M, int K, int Nout,
    const float* __restrict__ bias0, const float* __restrict__ bias1,
    const float* __restrict__ bias2, const float* __restrict__ bias3,
    unsigned short* __restrict__ outB, float* __restrict__ outF,
    const float* __restrict__ res)
{
  __shared__ unsigned short lA[128*64];
  __shared__ unsigned short lB[128*64];
  const int tid  = threadIdx.x;
  const int lane = tid & 63;
  const int wid  = tid >> 6;
  const int bm = blockIdx.x * 128;
  const int bn = blockIdx.y * 128;
  const int wm = (wid >> 1) * 64;
  const int wn = (wid & 1) * 64;
  f32x4 acc[4][4];
  #pragma unroll
  for (int m=0;m<4;m++)
    #pragma unroll
    for (int n=0;n<4;n++) acc[m][n] = (f32x4)0.f;

  for (int kt = 0; kt < K; kt += 64) {
    #pragma unroll
    for (int it = 0; it < 4; ++it) {
      int chunk = it*256 + tid;
      int row = chunk >> 3;
      int cin = chunk & 7;
      int scol = (cin ^ (row & 7)) * 8;   // pre-swizzled global source (rule 21)
      int ga = bm + row; if (ga >= M) ga = M - 1;
      const unsigned short* gpA = A + (size_t)ga * K + kt + scol;
      __builtin_amdgcn_global_load_lds(
        (const __attribute__((address_space(1))) void*)gpA,
        (__attribute__((address_space(3))) void*)(&lA[(it*256 + (wid<<6)) * 8]),
        16, 0, 0);
      const unsigned short* gpB = Bt + (size_t)(bn + row) * K + kt + scol;
      __builtin_amdgcn_global_load_lds(
        (const __attribute__((address_space(1))) void*)gpB,
        (__attribute__((address_space(3))) void*)(&lB[(it*256 + (wid<<6)) * 8]),
        16, 0, 0);
    }
    asm volatile("s_waitcnt vmcnt(0)" ::: "memory");
    __syncthreads();
    #pragma unroll
    for (int ks = 0; ks < 2; ++ks) {
      short8 af[4], bfr[4];
      #pragma unroll
      for (int m=0;m<4;m++){
        int r = wm + m*16 + (lane & 15);
        int ch = (ks*4 + (lane >> 4)) ^ (r & 7);
        af[m] = *(const short8*)&lA[r*64 + ch*8];
      }
      #pragma unroll
      for (int n=0;n<4;n++){
        int r = wn + n*16 + (lane & 15);
        int ch = (ks*4 + (lane >> 4)) ^ (r & 7);
        bfr[n] = *(const short8*)&lB[r*64 + ch*8];
      }
      #pragma unroll
      for (int m=0;m<4;m++)
        #pragma unroll
        for (int n=0;n<4;n++)
          acc[m][n] = __builtin_amdgcn_mfma_f32_16x16x32_bf16(af[m], bfr[n], acc[m][n], 0,0,0);
    }
    __syncthreads();
  }

  #pragma unroll
  for (int m=0;m<4;m++){
    int row0 = bm + wm + m*16 + ((lane >> 4) << 2);
    #pragma unroll
    for (int n=0;n<4;n++){
      int col = bn + wn + n*16 + (lane & 15);
      #pragma unroll
      for (int r=0;r<4;r++){
        int row = row0 + r;
        if (row < M){
          float v = acc[m][n][r];
          if (MODE == 0){
            float b = (col < 512) ? bias0[col]
                    : (col < 1024) ? bias1[col-512]
                    : (col < 1536) ? bias2[col-1024] : bias3[col-1536];
            v += b;
            if (col < 1536) outB[(size_t)row*1536 + col] = f2b(v);
            else            outF[(size_t)row*512 + (col - 1536)] = v;
          } else if (MODE == 1){
            v += bias0[col];
            v = fmaxf(v, 0.0f);
            outB[(size_t)row*Nout + col] = f2b(v);
          } else {
            v += bias0[col] + res[(size_t)row*512 + col];
            outF[(size_t)row*512 + col] = v;
          }
        }
      }
    }
  }
}

// ---------------- attention: one wave per destination node, online softmax ----------------
__global__ __launch_bounds__(256) void attn_k(
  const unsigned short* __restrict__ qkv, const float* __restrict__ skip,
  const float* __restrict__ enc, const int* __restrict__ rowstart,
  const int* __restrict__ csrc, float* __restrict__ xout, int N)
{
  int n = blockIdx.x*4 + (threadIdx.x>>6);
  if (n >= N) return;
  int lane = threadIdx.x & 63;
  const short8 qv = *(const short8*)&qkv[(size_t)n*1536 + lane*8];
  float qf[8];
  #pragma unroll
  for (int j=0;j<8;j++) qf[j] = b2f(((const unsigned short*)&qv)[j]);
  float m = -__builtin_inff(), l = 0.f;
  float acc[8] = {0.f,0.f,0.f,0.f,0.f,0.f,0.f,0.f};
  int e = rowstart[n], e1 = rowstart[n+1];
  for (; e < e1; ++e){
    int s = csrc[e];
    const short8 kv = *(const short8*)&qkv[(size_t)s*1536 + 512 + lane*8];
    float dot = 0.f;
    #pragma unroll
    for (int j=0;j<8;j++) dot += qf[j]*b2f(((const unsigned short*)&kv)[j]);
    dot += __shfl_xor(dot,1); dot += __shfl_xor(dot,2); dot += __shfl_xor(dot,4);
    float a = dot * 0.125f;               // 1/sqrt(64)
    float mn = fmaxf(m, a);
    float corr = __expf(m - mn);
    float p = __expf(a - mn);
    l = l*corr + p;
    const short8 vv = *(const short8*)&qkv[(size_t)s*1536 + 1024 + lane*8];
    #pragma unroll
    for (int j=0;j<8;j++) acc[j] = acc[j]*corr + p*b2f(((const unsigned short*)&vv)[j]);
    m = mn;
  }
  float inv = 1.f/(l + 1e-16f);
  size_t base = (size_t)n*512 + (size_t)lane*8;
  #pragma unroll
  for (int j=0;j<8;j++) xout[base+j] = acc[j]*inv + skip[base+j] + enc[base+j];
}

// ---------------- LayerNorm (wave per row) ----------------
// MODE 0: write f32 h + bf16 hb.   MODE 1: write f32 (ln + addv) to outF.
template<int MODE>
__global__ __launch_bounds__(256) void ln_k(const float* __restrict__ x,
  const float* __restrict__ g, const float* __restrict__ b,
  float* __restrict__ outF, unsigned short* __restrict__ outB,
  const float* __restrict__ addv, int N)
{
  int n = blockIdx.x*4 + (threadIdx.x>>6);
  if (n >= N) return;
  int lane = threadIdx.x & 63;
  size_t base = (size_t)n*512 + (size_t)lane*8;
  const float4* p = (const float4*)(x + base);
  float4 a0 = p[0], a1 = p[1];
  float v[8] = {a0.x,a0.y,a0.z,a0.w,a1.x,a1.y,a1.z,a1.w};
  float s=0.f, ss=0.f;
  #pragma unroll
  for (int j=0;j<8;j++){ s += v[j]; ss += v[j]*v[j]; }
  #pragma unroll
  for (int o=1;o<64;o<<=1){ s += __shfl_xor(s,o); ss += __shfl_xor(ss,o); }
  float mean = s * (1.f/512.f);
  float var  = ss * (1.f/512.f) - mean*mean;
  float rstd = rsqrtf(var + 1e-5f);
  #pragma unroll
  for (int j=0;j<8;j++){
    int c = lane*8 + j;
    float o = (v[j]-mean)*rstd*g[c] + b[c];
    if (MODE == 0){ outF[base+j] = o; outB[base+j] = f2b(o); }
    else          { outF[base+j] = o + addv[base+j]; }
  }
}

extern "C" void kernel_launch(void* const* d_in, const int* in_sizes, int n_in,
                              void* d_out, int out_size, void* d_ws, size_t ws_size,
                              hipStream_t stream)
{
  const float* x0  = (const float*)d_in[0];
  const int*  eidx = (const int*)d_in[1];
  const float* Wq  = (const float*)d_in[4];
  const float* bq  = (const float*)d_in[5];
  const float* Wk  = (const float*)d_in[6];
  const float* bk  = (const float*)d_in[7];
  const float* Wv  = (const float*)d_in[8];
  const float* bv  = (const float*)d_in[9];
  const float* Wsk = (const float*)d_in[10];
  const float* bs  = (const float*)d_in[11];
  const float* W1  = (const float*)d_in[12];
  const float* b1  = (const float*)d_in[13];
  const float* W2  = (const float*)d_in[14];
  const float* b2  = (const float*)d_in[15];
  const float* lng = (const float*)d_in[16];
  const float* lnb = (const float*)d_in[17];

  const int N = in_sizes[0] / 512;
  const int E = in_sizes[1] / 2;
  const int* esrc = eidx;
  const int* edst = eidx + E;

  char* ws = (char*)d_ws;
  size_t off = 0;
  auto alloc = [&](size_t bytes)->char*{
    char* p = ws + off; off = (off + bytes + 255) & ~(size_t)255; return p;
  };
  unsigned short* wtqkvs = (unsigned short*)alloc((size_t)2*2048*512*2);
  unsigned short* wt1    = (unsigned short*)alloc((size_t)1024*512*2);
  unsigned short* wt2    = (unsigned short*)alloc((size_t)512*1024*2);
  unsigned short* qkv    = (unsigned short*)alloc((size_t)N*1536*2);
  float*          skip   = (float*)alloc((size_t)N*512*4);   // later: h
  float*          xbuf   = (float*)alloc((size_t)N*512*4);
  unsigned short* xb     = (unsigned short*)alloc((size_t)N*512*2); // later: hb
  int* deg      = (int*)alloc((size_t)N*4);
  int* rowstart = (int*)alloc((size_t)(N+1)*4);
  int* cursor   = (int*)alloc((size_t)N*4);
  int* csrc     = (int*)alloc((size_t)E*4);
  unsigned short* tbuf = qkv;  // alias: qkv dead by FFN time, N*1024*2 <= N*1536*2

  // CSR build
  hipMemsetAsync(deg, 0, (size_t)N*4, stream);
  count_k<<<(E+255)/256, 256, 0, stream>>>(edst, deg, E);
  scan_k<<<1, 1024, 0, stream>>>(deg, rowstart, cursor, N);
  fill_k<<<(E+255)/256, 256, 0, stream>>>(esrc, edst, cursor, csrc, E);

  // weight transposes (Wt[o][i] = W[i][o], bf16)
  for (int l = 0; l < 2; ++l){
    unsigned short* base = wtqkvs + (size_t)l*2048*512;
    transpose_k<<<(512*64+255)/256, 256, 0, stream>>>(Wq  + (size_t)l*512*512, base,               512, 512);
    transpose_k<<<(512*64+255)/256, 256, 0, stream>>>(Wk  + (size_t)l*512*512, base +  512*512,    512, 512);
    transpose_k<<<(512*64+255)/256, 256, 0, stream>>>(Wv  + (size_t)l*512*512, base + 1024*512,    512, 512);
    transpose_k<<<(512*64+255)/256, 256, 0, stream>>>(Wsk + (size_t)l*512*512, base + 1536*512,    512, 512);
  }
  transpose_k<<<(1024*64+255)/256, 256, 0, stream>>>(W1, wt1, 512, 1024);
  transpose_k<<<(512*128+255)/256, 256, 0, stream>>>(W2, wt2, 1024, 512);

  const int cvtBlocks = (int)(((size_t)N*512/8 + 255)/256);
  const int rowBlocks = (N + 3)/4;

  // 2 TransformerConv layers
  for (int l = 0; l < 2; ++l){
    cvt_k<<<cvtBlocks, 256, 0, stream>>>(l == 0 ? x0 : xbuf, xb, (size_t)N*512);
    dim3 g0((N+127)/128, 2048/128);
    gemm_k<0><<<g0, 256, 0, stream>>>(xb, wtqkvs + (size_t)l*2048*512, N, 512, 2048,
        bq + l*512, bk + l*512, bv + l*512, bs + l*512, qkv, skip, nullptr);
    attn_k<<<rowBlocks, 256, 0, stream>>>(qkv, skip, x0, rowstart, csrc, xbuf, N);
  }

  // LN1 -> h (f32, in skip) + hb (bf16, in xb)
  ln_k<0><<<rowBlocks, 256, 0, stream>>>(xbuf, lng, lnb, skip, xb, nullptr, N);
  // FFN1: relu(hb @ W1 + b1) -> bf16 t
  dim3 g1((N+127)/128, 1024/128);
  gemm_k<1><<<g1, 256, 0, stream>>>(xb, wt1, N, 512, 1024,
      b1, nullptr, nullptr, nullptr, tbuf, nullptr, nullptr);
  // FFN2: t @ W2 + b2 + h -> f32 y (in xbuf)
  dim3 g2((N+127)/128, 512/128);
  gemm_k<2><<<g2, 256, 0, stream>>>(tbuf, wt2, N, 1024, 512,
      b2, nullptr, nullptr, nullptr, nullptr, xbuf, skip);
  // LN2 + enc -> d_out
  ln_k<1><<<rowBlocks, 256, 0, stream>>>(xbuf, lng, lnb, (float*)d_out, nullptr, x0, N);
}

// Round 2
// 671.375 us; speedup vs baseline: 1.0470x; 1.0470x over previous
//
#include <hip/hip_runtime.h>

typedef __attribute__((ext_vector_type(8))) short short8;
typedef __attribute__((ext_vector_type(4))) float f32x4;

__device__ __forceinline__ unsigned short f2b(float f){
  union { float f; unsigned u; } x; x.f = f;
  unsigned r = x.u + 0x7fffu + ((x.u >> 16) & 1u);
  return (unsigned short)(r >> 16);
}
__device__ __forceinline__ float b2f(unsigned short v){
  union { unsigned u; float f; } x; x.u = ((unsigned)v) << 16; return x.f;
}

// ---------------- CSR build ----------------
__global__ void count_k(const int* __restrict__ dst, int* __restrict__ deg, int E){
  int e = blockIdx.x*256 + threadIdx.x;
  if (e < E) atomicAdd(&deg[dst[e]], 1);
}

__global__ void scan_k(const int* __restrict__ deg, int* __restrict__ rowstart,
                       int* __restrict__ cursor, int n)
{
  __shared__ int wsum[16];
  __shared__ int carry_s;
  int tid = threadIdx.x, lane = tid & 63, wv = tid >> 6;
  if (tid == 0) carry_s = 0;
  __syncthreads();
  for (int base = 0; base < n; base += 1024){
    int i = base + tid;
    int v = (i < n) ? deg[i] : 0;
    int xv = v;
    #pragma unroll
    for (int o=1;o<64;o<<=1){ int t = __shfl_up(xv, o, 64); if (lane >= o) xv += t; }
    if (lane == 63) wsum[wv] = xv;
    __syncthreads();
    if (tid < 16){
      int w = wsum[tid];
      #pragma unroll
      for (int o=1;o<16;o<<=1){ int t = __shfl_up(w, o, 64); if (tid >= o) w += t; }
      wsum[tid] = w;
    }
    __syncthreads();
    int woff = (wv == 0) ? 0 : wsum[wv-1];
    int carry = carry_s;
    if (i < n){ int excl = carry + woff + xv - v; rowstart[i] = excl; cursor[i] = excl; }
    int total = wsum[15];
    __syncthreads();
    if (tid == 0) carry_s = carry + total;
    __syncthreads();
  }
  if (threadIdx.x == 0) rowstart[n] = carry_s;
}

__global__ void fill_k(const int* __restrict__ src, const int* __restrict__ dst,
                       int* __restrict__ cursor, int* __restrict__ csrc, int E){
  int e = blockIdx.x*256 + threadIdx.x;
  if (e < E){
    int p = atomicAdd(&cursor[dst[e]], 1);
    csrc[p] = src[e];
  }
}

// ---------------- weight transpose + bf16 convert: Wt[o][i] = W[i][o] ----------------
__global__ void transpose_k(const float* __restrict__ W, unsigned short* __restrict__ Wt,
                            int r, int c){
  int idx = blockIdx.x*256 + threadIdx.x;
  int total = c * (r >> 3);
  if (idx >= total) return;
  int o = idx % c;
  int i0 = (idx / c) << 3;
  short8 vv;
  #pragma unroll
  for (int j=0;j<8;j++) ((unsigned short*)&vv)[j] = f2b(W[(size_t)(i0+j)*c + o]);
  *(short8*)&Wt[(size_t)o*r + i0] = vv;
}

// ---------------- f32 -> bf16 convert ----------------
__global__ void cvt_k(const float* __restrict__ in, unsigned short* __restrict__ out, size_t n){
  size_t i = ((size_t)blockIdx.x*256 + threadIdx.x)*8;
  if (i >= n) return;
  const float4* p = (const float4*)(in + i);
  float4 a0 = p[0], a1 = p[1];
  short8 vv;
  ((unsigned short*)&vv)[0] = f2b(a0.x); ((unsigned short*)&vv)[1] = f2b(a0.y);
  ((unsigned short*)&vv)[2] = f2b(a0.z); ((unsigned short*)&vv)[3] = f2b(a0.w);
  ((unsigned short*)&vv)[4] = f2b(a1.x); ((unsigned short*)&vv)[5] = f2b(a1.y);
  ((unsigned short*)&vv)[6] = f2b(a1.z); ((unsigned short*)&vv)[7] = f2b(a1.w);
  *(short8*)&out[i] = vv;
}

// ---------------- GEMM: A[M][KC] bf16 x Bt[NN*128][KC] bf16, depth-2 pipeline ----------------
// MODE 0: QKVS  (bias split; cols<1536 -> bf16 outB[row][1536], else bf16 outB2[row][512])
// MODE 1: FFN1  (bias + relu -> bf16 outB[row][NN*128])
// MODE 2: FFN2  (bias + res  -> f32 outF[row][512])
template<int MODE, int KC, int NN>
__global__ __launch_bounds__(256) void gemm_k(
    const unsigned short* __restrict__ A,
    const unsigned short* __restrict__ Bt,
    int M,
    const float* __restrict__ bias0, const float* __restrict__ bias1,
    const float* __restrict__ bias2, const float* __restrict__ bias3,
    unsigned short* __restrict__ outB, unsigned short* __restrict__ outB2,
    float* __restrict__ outF, const float* __restrict__ res)
{
  __shared__ unsigned short lA[2][128*64];
  __shared__ unsigned short lB[2][128*64];
  const int tid  = threadIdx.x;
  const int lane = tid & 63;
  const int wid  = tid >> 6;

  // bijective XCD-chunked swizzle (m204): contiguous swz range per XCD,
  // N-block fastest within chunk -> A panel reused, B panel L2-resident.
  const int nwg = gridDim.x;
  {
  }
  int id = blockIdx.x;
  int q = nwg >> 3, r = nwg & 7;
  int xc = id & 7, yy = id >> 3;
  int swz = (xc < r ? xc*(q+1) : r*(q+1) + (xc-r)*q) + yy;
  const int bm = (swz / NN) * 128;
  const int bn = (swz % NN) * 128;
  const int wm = (wid >> 1) * 64;
  const int wn = (wid & 1) * 64;

  f32x4 acc[4][4];
  #pragma unroll
  for (int m=0;m<4;m++)
    #pragma unroll
    for (int n=0;n<4;n++) acc[m][n] = (f32x4)0.f;

  constexpr int NT = KC / 64;

  auto STAGE = [&](int buf, int kt){
    #pragma unroll
    for (int it = 0; it < 4; ++it) {
      int chunk = it*256 + tid;
      int row = chunk >> 3;
      int cin = chunk & 7;
      int scol = (cin ^ (row & 7)) * 8;   // pre-swizzled global source (rule 21)
      int ga = bm + row; if (ga >= M) ga = M - 1;
      __builtin_amdgcn_global_load_lds(
        (const __attribute__((address_space(1))) void*)(A + (size_t)ga * KC + kt + scol),
        (__attribute__((address_space(3))) void*)(&lA[buf][(it*256 + (wid<<6)) * 8]),
        16, 0, 0);
      __builtin_amdgcn_global_load_lds(
        (const __attribute__((address_space(1))) void*)(Bt + (size_t)(bn + row) * KC + kt + scol),
        (__attribute__((address_space(3))) void*)(&lB[buf][(it*256 + (wid<<6)) * 8]),
        16, 0, 0);
    }
  };

  auto COMPUTE = [&](int buf){
    #pragma unroll
    for (int ks = 0; ks < 2; ++ks) {
      short8 af[4], bfr[4];
      #pragma unroll
      for (int m=0;m<4;m++){
        int rr = wm + m*16 + (lane & 15);
        int ch = (ks*4 + (lane >> 4)) ^ (rr & 7);
        af[m] = *(const short8*)&lA[buf][rr*64 + ch*8];
      }
      #pragma unroll
      for (int n=0;n<4;n++){
        int rr = wn + n*16 + (lane & 15);
        int ch = (ks*4 + (lane >> 4)) ^ (rr & 7);
        bfr[n] = *(const short8*)&lB[buf][rr*64 + ch*8];
      }
      #pragma unroll
      for (int m=0;m<4;m++)
        #pragma unroll
        for (int n=0;n<4;n++)
          acc[m][n] = __builtin_amdgcn_mfma_f32_16x16x32_bf16(af[m], bfr[n], acc[m][n], 0,0,0);
    }
  };

  // depth-2 pipeline: tiles t and t+1 in flight; counted vmcnt keeps
  // next-tile loads pending across barriers (never drain to 0 mid-loop).
  STAGE(0, 0);
  if (NT > 1) STAGE(1, 64);
  #pragma unroll
  for (int t = 0; t < NT; ++t){
    if (t == NT-1) asm volatile("s_waitcnt vmcnt(0)" ::: "memory");
    else           asm volatile("s_waitcnt vmcnt(8)" ::: "memory");
    __builtin_amdgcn_s_barrier();
    COMPUTE(t & 1);
    asm volatile("s_waitcnt lgkmcnt(0)" ::: "memory");  // pin ds_reads before barrier
    __builtin_amdgcn_s_barrier();
    if (t + 2 < NT) STAGE(t & 1, (t+2)*64);
  }

  #pragma unroll
  for (int m=0;m<4;m++){
    int row0 = bm + wm + m*16 + ((lane >> 4) << 2);
    #pragma unroll
    for (int n=0;n<4;n++){
      int col = bn + wn + n*16 + (lane & 15);
      #pragma unroll
      for (int r4=0;r4<4;r4++){
        int row = row0 + r4;
        if (row < M){
          float v = acc[m][n][r4];
          if (MODE == 0){
            float b = (col < 512) ? bias0[col]
                    : (col < 1024) ? bias1[col-512]
                    : (col < 1536) ? bias2[col-1024] : bias3[col-1536];
            v += b;
            if (col < 1536) outB[(size_t)row*1536 + col] = f2b(v);
            else            outB2[(size_t)row*512 + (col - 1536)] = f2b(v);
          } else if (MODE == 1){
            v += bias0[col];
            v = fmaxf(v, 0.0f);
            outB[(size_t)row*(NN*128) + col] = f2b(v);
          } else {
            v += bias0[col] + res[(size_t)row*512 + col];
            outF[(size_t)row*512 + col] = v;
          }
        }
      }
    }
  }
}

// ---------------- attention: one wave per destination node, online softmax ----------------
__global__ __launch_bounds__(256) void attn_k(
  const unsigned short* __restrict__ qkv, const unsigned short* __restrict__ skipb,
  const float* __restrict__ enc, const int* __restrict__ rowstart,
  const int* __restrict__ csrc, float* __restrict__ xout,
  unsigned short* __restrict__ xoutb, int N)
{
  int n = blockIdx.x*4 + (threadIdx.x>>6);
  if (n >= N) return;
  int lane = threadIdx.x & 63;
  const short8 qv = *(const short8*)&qkv[(size_t)n*1536 + lane*8];
  float qf[8];
  #pragma unroll
  for (int j=0;j<8;j++) qf[j] = b2f(((const unsigned short*)&qv)[j]);
  float m = -__builtin_inff(), l = 0.f;
  float acc[8] = {0.f,0.f,0.f,0.f,0.f,0.f,0.f,0.f};
  int e = rowstart[n], e1 = rowstart[n+1];
  for (; e < e1; ++e){
    int s = csrc[e];
    const short8 kv = *(const short8*)&qkv[(size_t)s*1536 + 512 + lane*8];
    float dot = 0.f;
    #pragma unroll
    for (int j=0;j<8;j++) dot += qf[j]*b2f(((const unsigned short*)&kv)[j]);
    dot += __shfl_xor(dot,1); dot += __shfl_xor(dot,2); dot += __shfl_xor(dot,4);
    float a = dot * 0.125f;               // 1/sqrt(64)
    float mn = fmaxf(m, a);
    float corr = __expf(m - mn);
    float p = __expf(a - mn);
    l = l*corr + p;
    const short8 vv = *(const short8*)&qkv[(size_t)s*1536 + 1024 + lane*8];
    #pragma unroll
    for (int j=0;j<8;j++) acc[j] = acc[j]*corr + p*b2f(((const unsigned short*)&vv)[j]);
    m = mn;
  }
  float inv = 1.f/(l + 1e-16f);
  size_t base = (size_t)n*512 + (size_t)lane*8;
  const short8 sv = *(const short8*)&skipb[base];
  short8 ob;
  #pragma unroll
  for (int j=0;j<8;j++){
    float o = acc[j]*inv + b2f(((const unsigned short*)&sv)[j]) + enc[base+j];
    xout[base+j] = o;
    ((unsigned short*)&ob)[j] = f2b(o);
  }
  *(short8*)&xoutb[base] = ob;
}

// ---------------- LayerNorm (wave per row) ----------------
// MODE 0: write f32 h + bf16 hb.   MODE 1: write f32 (ln + addv) to outF.
template<int MODE>
__global__ __launch_bounds__(256) void ln_k(const float* __restrict__ x,
  const float* __restrict__ g, const float* __restrict__ b,
  float* __restrict__ outF, unsigned short* __restrict__ outB,
  const float* __restrict__ addv, int N)
{
  int n = blockIdx.x*4 + (threadIdx.x>>6);
  if (n >= N) return;
  int lane = threadIdx.x & 63;
  size_t base = (size_t)n*512 + (size_t)lane*8;
  const float4* p = (const float4*)(x + base);
  float4 a0 = p[0], a1 = p[1];
  float v[8] = {a0.x,a0.y,a0.z,a0.w,a1.x,a1.y,a1.z,a1.w};
  float s=0.f, ss=0.f;
  #pragma unroll
  for (int j=0;j<8;j++){ s += v[j]; ss += v[j]*v[j]; }
  #pragma unroll
  for (int o=1;o<64;o<<=1){ s += __shfl_xor(s,o); ss += __shfl_xor(ss,o); }
  float mean = s * (1.f/512.f);
  float var  = ss * (1.f/512.f) - mean*mean;
  float rstd = rsqrtf(var + 1e-5f);
  #pragma unroll
  for (int j=0;j<8;j++){
    int c = lane*8 + j;
    float o = (v[j]-mean)*rstd*g[c] + b[c];
    if (MODE == 0){ outF[base+j] = o; outB[base+j] = f2b(o); }
    else          { outF[base+j] = o + addv[base+j]; }
  }
}

extern "C" void kernel_launch(void* const* d_in, const int* in_sizes, int n_in,
                              void* d_out, int out_size, void* d_ws, size_t ws_size,
                              hipStream_t stream)
{
  const float* x0  = (const float*)d_in[0];
  const int*  eidx = (const int*)d_in[1];
  const float* Wq  = (const float*)d_in[4];
  const float* bq  = (const float*)d_in[5];
  const float* Wk  = (const float*)d_in[6];
  const float* bk  = (const float*)d_in[7];
  const float* Wv  = (const float*)d_in[8];
  const float* bv  = (const float*)d_in[9];
  const float* Wsk = (const float*)d_in[10];
  const float* bs  = (const float*)d_in[11];
  const float* W1  = (const float*)d_in[12];
  const float* b1  = (const float*)d_in[13];
  const float* W2  = (const float*)d_in[14];
  const float* b2  = (const float*)d_in[15];
  const float* lng = (const float*)d_in[16];
  const float* lnb = (const float*)d_in[17];

  const int N = in_sizes[0] / 512;
  const int E = in_sizes[1] / 2;
  const int* esrc = eidx;
  const int* edst = eidx + E;

  char* ws = (char*)d_ws;
  size_t off = 0;
  auto alloc = [&](size_t bytes)->char*{
    char* p = ws + off; off = (off + bytes + 255) & ~(size_t)255; return p;
  };
  unsigned short* wtqkvs = (unsigned short*)alloc((size_t)2*2048*512*2);
  unsigned short* wt1    = (unsigned short*)alloc((size_t)1024*512*2);
  unsigned short* wt2    = (unsigned short*)alloc((size_t)512*1024*2);
  unsigned short* qkv    = (unsigned short*)alloc((size_t)N*1536*2);
  float*          skip   = (float*)alloc((size_t)N*512*4);   // f32 h after LN1
  float*          xbuf   = (float*)alloc((size_t)N*512*4);
  unsigned short* xb     = (unsigned short*)alloc((size_t)N*512*2); // bf16 x / hb
  unsigned short* skipb  = (unsigned short*)alloc((size_t)N*512*2); // bf16 skip proj
  int* deg      = (int*)alloc((size_t)N*4);
  int* rowstart = (int*)alloc((size_t)(N+1)*4);
  int* cursor   = (int*)alloc((size_t)N*4);
  int* csrc     = (int*)alloc((size_t)E*4);
  unsigned short* tbuf = qkv;  // alias: qkv dead by FFN time, N*1024*2 <= N*1536*2

  // CSR build
  hipMemsetAsync(deg, 0, (size_t)N*4, stream);
  count_k<<<(E+255)/256, 256, 0, stream>>>(edst, deg, E);
  scan_k<<<1, 1024, 0, stream>>>(deg, rowstart, cursor, N);
  fill_k<<<(E+255)/256, 256, 0, stream>>>(esrc, edst, cursor, csrc, E);

  // weight transposes (Wt[o][i] = W[i][o], bf16)
  for (int l = 0; l < 2; ++l){
    unsigned short* base = wtqkvs + (size_t)l*2048*512;
    transpose_k<<<(512*64+255)/256, 256, 0, stream>>>(Wq  + (size_t)l*512*512, base,            512, 512);
    transpose_k<<<(512*64+255)/256, 256, 0, stream>>>(Wk  + (size_t)l*512*512, base +  512*512, 512, 512);
    transpose_k<<<(512*64+255)/256, 256, 0, stream>>>(Wv  + (size_t)l*512*512, base + 1024*512, 512, 512);
    transpose_k<<<(512*64+255)/256, 256, 0, stream>>>(Wsk + (size_t)l*512*512, base + 1536*512, 512, 512);
  }
  transpose_k<<<(1024*64+255)/256, 256, 0, stream>>>(W1, wt1, 512, 1024);
  transpose_k<<<(512*128+255)/256, 256, 0, stream>>>(W2, wt2, 1024, 512);

  const int cvtBlocks = (int)(((size_t)N*512/8 + 255)/256);
  const int rowBlocks = (N + 3)/4;
  const int MB = (N + 127)/128;   // 157

  // 2 TransformerConv layers
  cvt_k<<<cvtBlocks, 256, 0, stream>>>(x0, xb, (size_t)N*512);
  for (int l = 0; l < 2; ++l){
    gemm_k<0,512,16><<<MB*16, 256, 0, stream>>>(xb, wtqkvs + (size_t)l*2048*512, N,
        bq + l*512, bk + l*512, bv + l*512, bs + l*512, qkv, skipb, nullptr, nullptr);
    attn_k<<<rowBlocks, 256, 0, stream>>>(qkv, skipb, x0, rowstart, csrc, xbuf, xb, N);
  }

  // LN1 -> h (f32, in skip) + hb (bf16, in xb)
  ln_k<0><<<rowBlocks, 256, 0, stream>>>(xbuf, lng, lnb, skip, xb, nullptr, N);
  // FFN1: relu(hb @ W1 + b1) -> bf16 t
  gemm_k<1,512,8><<<MB*8, 256, 0, stream>>>(xb, wt1, N,
      b1, nullptr, nullptr, nullptr, tbuf, nullptr, nullptr, nullptr);
  // FFN2: t @ W2 + b2 + h -> f32 y (in xbuf)
  gemm_k<2,1024,4><<<MB*4, 256, 0, stream>>>(tbuf, wt2, N,
      b2, nullptr, nullptr, nullptr, nullptr, nullptr, xbuf, skip);
  // LN2 + enc -> d_out
  ln_k<1><<<rowBlocks, 256, 0, stream>>>(xbuf, lng, lnb, (float*)d_out, nullptr, x0, N);
}